// Round 2
// baseline (799.104 us; speedup 1.0000x reference)
//
#include <hip/hip_runtime.h>

#define N_EDGES 250000
#define N_ATOMS 10000

// ---------------------------------------------------------------------------
// Bucketing kernels: build per-center edge lists so the density kernel can
// accumulate in registers with zero global atomics on the output.
// ---------------------------------------------------------------------------

__global__ void zero_counts_kernel(int* __restrict__ counts) {
    int i = blockIdx.x * blockDim.x + threadIdx.x;
    if (i < N_ATOMS) counts[i] = 0;
}

__global__ void count_edges_kernel(const int* __restrict__ centers,
                                   int* __restrict__ counts) {
    int e = blockIdx.x * blockDim.x + threadIdx.x;
    if (e < N_EDGES) atomicAdd(&counts[centers[e]], 1);
}

// Single-block exclusive scan over N_ATOMS counts -> offsets[0..N_ATOMS]
// (also writes a second copy "cursor" used as the fill cursor).
__global__ void scan_offsets_kernel(const int* __restrict__ counts,
                                    int* __restrict__ offsets,
                                    int* __restrict__ cursor) {
    __shared__ int sdata[256];
    const int t = threadIdx.x;
    const int CH = 40;  // ceil(10000/256)
    const int base = t * CH;
    int sum = 0;
    for (int i = 0; i < CH; ++i) {
        int idx = base + i;
        if (idx < N_ATOMS) sum += counts[idx];
    }
    sdata[t] = sum;
    __syncthreads();
    // Hillis-Steele inclusive scan over 256 partials (read-all, barrier,
    // write-all, barrier -> race-free).
    for (int off = 1; off < 256; off <<= 1) {
        int v = (t >= off) ? sdata[t - off] : 0;
        __syncthreads();
        sdata[t] += v;
        __syncthreads();
    }
    int incl = sdata[t];
    int run = incl - sum;  // exclusive prefix
    for (int i = 0; i < CH; ++i) {
        int idx = base + i;
        if (idx < N_ATOMS) {
            offsets[idx] = run;
            cursor[idx] = run;
            run += counts[idx];
        }
    }
    if (t == 255) offsets[N_ATOMS] = incl;  // total == N_EDGES
}

__global__ void fill_list_kernel(const int* __restrict__ centers,
                                 int* __restrict__ cursor,
                                 int* __restrict__ elist) {
    int e = blockIdx.x * blockDim.x + threadIdx.x;
    if (e < N_EDGES) {
        int p = atomicAdd(&cursor[centers[e]], 1);
        elist[p] = e;
    }
}

// ---------------------------------------------------------------------------
// Density kernel: one wave (64 lanes) per atom. Lane t owns channels
// k == t (mod 64). Accumulators: l=0: 4, l=1: 3x3, l=2: 5x2, l=3: 7 -> 30 f32.
// All global loads are lane-contiguous dwords (coalesced); sh loads are
// wave-uniform (broadcast). Output written once, coalesced, no atomics.
// ---------------------------------------------------------------------------

__global__ __launch_bounds__(256) void density_kernel(
    const float* __restrict__ sh0, const float* __restrict__ sh1,
    const float* __restrict__ sh2, const float* __restrict__ sh3,
    const float* __restrict__ rb0, const float* __restrict__ rb1,
    const float* __restrict__ rb2, const float* __restrict__ rb3,
    const float* __restrict__ emb, const int* __restrict__ neighbors,
    const int* __restrict__ offsets, const int* __restrict__ elist,
    float* __restrict__ out) {
    const int wave = threadIdx.x >> 6;
    const int a = blockIdx.x * 4 + wave;   // grid = 2500 blocks -> a < 10000
    const int t = threadIdx.x & 63;

    const int s = offsets[a];
    const int e = offsets[a + 1];

    float a0[4] = {0.f, 0.f, 0.f, 0.f};
    float a1[3][3] = {};
    float a2[5][2] = {};
    float a3[7] = {};

    for (int i = s; i < e; ++i) {
        const int eg = elist[i];
        const int nb = neighbors[eg];

        const float* er = emb + (size_t)nb * 256;
        const float em0 = er[t];
        const float em1 = er[t + 64];
        const float em2 = er[t + 128];
        const float em3 = er[t + 192];

        const float* r0 = rb0 + (size_t)eg * 256;
        const float* r1 = rb1 + (size_t)eg * 192;
        const float* r2 = rb2 + (size_t)eg * 128;
        const float* r3 = rb3 + (size_t)eg * 64;

        const float p00 = r0[t] * em0;
        const float p01 = r0[t + 64] * em1;
        const float p02 = r0[t + 128] * em2;
        const float p03 = r0[t + 192] * em3;
        const float p10 = r1[t] * em0;
        const float p11 = r1[t + 64] * em1;
        const float p12 = r1[t + 128] * em2;
        const float p20 = r2[t] * em0;
        const float p21 = r2[t + 64] * em1;
        const float p30 = r3[t] * em0;

        const float s0 = sh0[eg];
        a0[0] += s0 * p00;
        a0[1] += s0 * p01;
        a0[2] += s0 * p02;
        a0[3] += s0 * p03;

        const float* s1 = sh1 + (size_t)eg * 3;
#pragma unroll
        for (int m = 0; m < 3; ++m) {
            const float sm = s1[m];
            a1[m][0] += sm * p10;
            a1[m][1] += sm * p11;
            a1[m][2] += sm * p12;
        }
        const float* s2 = sh2 + (size_t)eg * 5;
#pragma unroll
        for (int m = 0; m < 5; ++m) {
            const float sm = s2[m];
            a2[m][0] += sm * p20;
            a2[m][1] += sm * p21;
        }
        const float* s3 = sh3 + (size_t)eg * 7;
#pragma unroll
        for (int m = 0; m < 7; ++m) {
            a3[m] += s3[m] * p30;
        }
    }

    // Output layout: concat of [10000,1,256], [10000,3,192], [10000,5,128],
    // [10000,7,64] in flat f32.
    const size_t O1 = (size_t)N_ATOMS * 256;
    const size_t O2 = O1 + (size_t)N_ATOMS * 3 * 192;
    const size_t O3 = O2 + (size_t)N_ATOMS * 5 * 128;

    float* o0 = out + (size_t)a * 256;
#pragma unroll
    for (int j = 0; j < 4; ++j) o0[t + 64 * j] = a0[j];

    float* o1 = out + O1 + (size_t)a * 3 * 192;
#pragma unroll
    for (int m = 0; m < 3; ++m)
#pragma unroll
        for (int j = 0; j < 3; ++j) o1[m * 192 + t + 64 * j] = a1[m][j];

    float* o2 = out + O2 + (size_t)a * 5 * 128;
#pragma unroll
    for (int m = 0; m < 5; ++m)
#pragma unroll
        for (int j = 0; j < 2; ++j) o2[m * 128 + t + 64 * j] = a2[m][j];

    float* o3 = out + O3 + (size_t)a * 7 * 64;
#pragma unroll
    for (int m = 0; m < 7; ++m) o3[m * 64 + t] = a3[m];
}

// ---------------------------------------------------------------------------

extern "C" void kernel_launch(void* const* d_in, const int* in_sizes, int n_in,
                              void* d_out, int out_size, void* d_ws, size_t ws_size,
                              hipStream_t stream) {
    // Input order = setup_inputs() dict INSERTION order, which interleaves
    // sh_l and rb_l inside the per-l loop:
    //   0: sh_0 [250000,1,1]   1: rb_0 [250000,256]
    //   2: sh_1 [250000,3,1]   3: rb_1 [250000,192]
    //   4: sh_2 [250000,5,1]   5: rb_2 [250000,128]
    //   6: sh_3 [250000,7,1]   7: rb_3 [250000,64]
    //   8: emb  [10000,1,256]  9: centers [250000]  10: neighbors [250000]
    const float* sh0 = (const float*)d_in[0];
    const float* rb0 = (const float*)d_in[1];
    const float* sh1 = (const float*)d_in[2];
    const float* rb1 = (const float*)d_in[3];
    const float* sh2 = (const float*)d_in[4];
    const float* rb2 = (const float*)d_in[5];
    const float* sh3 = (const float*)d_in[6];
    const float* rb3 = (const float*)d_in[7];
    const float* emb = (const float*)d_in[8];
    const int* centers = (const int*)d_in[9];
    const int* neighbors = (const int*)d_in[10];
    float* out = (float*)d_out;

    // Workspace layout (ints): counts[10000] | offsets[10001] | cursor[10000]
    // | elist[250000]  -> 1,120,004 bytes total.
    int* counts = (int*)d_ws;
    int* offsets = counts + N_ATOMS;
    int* cursor = offsets + (N_ATOMS + 1);
    int* elist = cursor + N_ATOMS;

    zero_counts_kernel<<<(N_ATOMS + 255) / 256, 256, 0, stream>>>(counts);
    count_edges_kernel<<<(N_EDGES + 255) / 256, 256, 0, stream>>>(centers, counts);
    scan_offsets_kernel<<<1, 256, 0, stream>>>(counts, offsets, cursor);
    fill_list_kernel<<<(N_EDGES + 255) / 256, 256, 0, stream>>>(centers, cursor, elist);
    density_kernel<<<N_ATOMS / 4, 256, 0, stream>>>(
        sh0, sh1, sh2, sh3, rb0, rb1, rb2, rb3, emb, neighbors, offsets, elist,
        out);
}